// Round 6
// baseline (298.035 us; speedup 1.0000x reference)
//
#include <hip/hip_runtime.h>
#include <hip/hip_fp16.h>
#include <math.h>

// Problem constants: NE=1e6, NR=1000, D=32, B=2^20, CURV=1
#define NR_ 1000
#define NE_ 1000000
#define D_ 32
#define HALF_ 16
#define EMB_DIM 33            // fp32 entity row: [x0, spatial(32)]
#define TAB_STRIDE 68         // precomputed relation row (272 B)
#define LROW 17               // LDS uints per staged row (odd -> 2-way banks = free)
#define H16_BYTES ((size_t)NE_ * 64)   // fp16 table: 16 uints/row, 64 B-aligned rows
#define REPACK_BLOCKS 62500   // 62500*256 = 16,000,000 = NE*16 repack threads

// ---------------------------------------------------------------------------
// Kernel 0 (fused prep): blocks [0, REPACK_BLOCKS) repack entity spatials
// fp32 -> fp16 into 64 B-aligned rows (one line per row gather afterwards;
// also leaves the 64 MB table L2/L3-resident for the main kernel). Blocks
// [REPACK_BLOCKS, +4) build the per-relation table:
//   [0:16) cos(rot)  [16:32) sin(rot)  [32:64) (sinh(vn)/vn)*0.1*trans
//   [64] cosh(rap0) [65] sinh(rap0) [66] cosh(vn) [67] pad
// ---------------------------------------------------------------------------
__global__ __launch_bounds__(256) void prep_kernel(
    const float* __restrict__ emb, const float* __restrict__ boost_w,
    const float* __restrict__ rot_w, const float* __restrict__ trans_w,
    unsigned int* __restrict__ h16, float* __restrict__ tab) {
  const int b = blockIdx.x;
  if (b < REPACK_BLOCKS) {
    int t = b * 256 + threadIdx.x;              // < 16,000,000
    int r = t >> 4, j = t & 15;
    const float* p = emb + (size_t)r * EMB_DIM + 1 + 2 * j;
    union { __half2 h; unsigned int u; } cvt;
    cvt.h = __half2(__float2half_rn(p[0]), __float2half_rn(p[1]));
    h16[t] = cvt.u;
    return;
  }
  int r = (b - REPACK_BLOCKS) * 256 + threadIdx.x;
  if (r >= NR_) return;
  const float* ro = rot_w   + (size_t)r * D_;
  const float* tr = trans_w + (size_t)r * D_;
  float* o = tab + (size_t)r * TAB_STRIDE;
  #pragma unroll
  for (int j = 0; j < HALF_; ++j) {
    float th = ro[j];
    o[j]         = cosf(th);
    o[HALF_ + j] = sinf(th);
  }
  float s2 = 0.f;
  #pragma unroll
  for (int j = 0; j < D_; ++j) { float v = tr[j]; s2 = fmaf(v, v, s2); }
  float vn  = sqrtf(fmaxf(0.01f * s2, 1e-6f));
  float k   = sinhf(vn) / vn * 0.1f;
  #pragma unroll
  for (int j = 0; j < D_; ++j) o[2 * HALF_ + j] = k * tr[j];
  float rap = fminf(fmaxf(boost_w[(size_t)r * D_], -2.f), 2.f);
  o[64] = coshf(rap);
  o[65] = sinhf(rap);
  o[66] = coshf(vn);
  o[67] = 0.f;
}

// ---------------------------------------------------------------------------
// Kernel 1: main scoring. Block=256 (4 waves), each wave owns 64 elements +
// a private LDS slice; barrier-free (per-wave DS ops retire in program
// order). LDS now holds fp16 rows: 64 rows x 17 uints -> 17408 B/block ->
// 8 blocks/CU = 32 waves/CU cap (was 16). Conversion fp16->fp32 happens on
// LDS read (2 v_cvt per uint, trivial VALU).
// Banks: reads (lane*17 + uu) % 32 -> exactly 2 lanes/bank (free, m136);
// writes (17e + 4q + m) % 32 per instr -> uniform 2 lanes/bank (free).
// x0/t0 recomputed as sqrt(1+sum(sp^2)) — same formula the reference uses.
// ---------------------------------------------------------------------------
__global__ __launch_bounds__(256) void lorentz_h16_kernel(
    const int* __restrict__ heads, const int* __restrict__ rels,
    const int* __restrict__ tails, const unsigned int* __restrict__ h16,
    const float* __restrict__ bias, const float* __restrict__ tab,
    float* __restrict__ out, int n) {
  __shared__ unsigned int buf[4][64 * LROW];   // 17408 B

  const int lane = threadIdx.x & 63;
  const int w    = threadIdx.x >> 6;
  const int gid  = blockIdx.x * 256 + threadIdx.x;
  const int i    = (gid < n) ? gid : (n - 1);   // clamp: lanes stay active

  const int hd = heads[i];
  const int rl = rels[i];
  const int tl = tails[i];
  const float bsum = bias[hd] + bias[tl];
  const float4* __restrict__ T =
      reinterpret_cast<const float4*>(tab + (size_t)rl * TAB_STRIDE);

  unsigned int* __restrict__ rb = buf[w];
  const int esub = lane >> 2;   // 0..15
  const int q    = lane & 3;    // 16 B chunk within row

  // ---- Phase A: stage 64 head rows (one 64 B line each; 16 rows/instr) ----
  #pragma unroll
  for (int k = 0; k < 4; ++k) {
    const int e   = k * 16 + esub;
    const int row = __shfl(hd, e, 64);
    const uint4 v = *reinterpret_cast<const uint4*>(
        h16 + (size_t)row * 16 + q * 4);        // 16 B-aligned
    unsigned int* dst = rb + e * LROW + q * 4;
    dst[0] = v.x; dst[1] = v.y; dst[2] = v.z; dst[3] = v.w;
  }

  // ---- Head compute: unpack own row, rotation + boost + translation ----
  const unsigned int* __restrict__ my = rb + lane * LROW;
  union U2 { unsigned int u; __half2 h; };
  float a[HALF_], b[HALF_];
  #pragma unroll
  for (int uu = 0; uu < 8; ++uu) {
    U2 ua; ua.u = my[uu];        // elements 2uu, 2uu+1   (a-half)
    U2 ub; ub.u = my[8 + uu];    // elements 16+2uu, 17+2uu (b-half)
    float2 fa = __half22float2(ua.h);
    float2 fb = __half22float2(ub.h);
    a[2 * uu] = fa.x; a[2 * uu + 1] = fa.y;
    b[2 * uu] = fb.x; b[2 * uu + 1] = fb.y;
  }
  float r[D_];
  float hsq = 0.f;
  #pragma unroll
  for (int qq = 0; qq < 4; ++qq) {
    float4 cv = T[qq];
    float4 sv = T[4 + qq];
    float cj[4] = {cv.x, cv.y, cv.z, cv.w};
    float sj[4] = {sv.x, sv.y, sv.z, sv.w};
    #pragma unroll
    for (int m = 0; m < 4; ++m) {
      int j = 4 * qq + m;
      hsq = fmaf(a[j], a[j], fmaf(b[j], b[j], hsq));
      r[j]         = cj[m] * a[j] - sj[m] * b[j];
      r[HALF_ + j] = sj[m] * a[j] + cj[m] * b[j];
    }
  }
  const float x0 = sqrtf(1.f + hsq);            // head time component
  float4 hv4 = T[16];                           // {cosh(rap), sinh(rap), cosh(vn), -}
  r[0] = fmaf(x0, hv4.y, r[0] * hv4.x);
  const float cvn = hv4.z;

  float rs[D_];
  float n2 = 0.f;
  #pragma unroll
  for (int qq = 0; qq < 8; ++qq) {
    float4 kv = T[8 + qq];
    float kj[4] = {kv.x, kv.y, kv.z, kv.w};
    #pragma unroll
    for (int m = 0; m < 4; ++m) {
      int j = 4 * qq + m;
      rs[j] = fmaf(cvn, r[j], kj[m]);
      n2 = fmaf(rs[j], rs[j], n2);
    }
  }
  const float ht0 = sqrtf(1.f + n2);

  // ---- Phase B: stage 64 tail rows into the same slice (per-wave DS
  // program order: head reads above already consumed it), then dot ----
  #pragma unroll
  for (int k = 0; k < 4; ++k) {
    const int e   = k * 16 + esub;
    const int row = __shfl(tl, e, 64);
    const uint4 v = *reinterpret_cast<const uint4*>(
        h16 + (size_t)row * 16 + q * 4);
    unsigned int* dst = rb + e * LROW + q * 4;
    dst[0] = v.x; dst[1] = v.y; dst[2] = v.z; dst[3] = v.w;
  }
  float dot = 0.f, tsq = 0.f;
  #pragma unroll
  for (int uu = 0; uu < 16; ++uu) {
    U2 ut; ut.u = my[uu];
    float2 ft = __half22float2(ut.h);
    dot = fmaf(rs[2 * uu], ft.x, fmaf(rs[2 * uu + 1], ft.y, dot));
    tsq = fmaf(ft.x, ft.x, fmaf(ft.y, ft.y, tsq));
  }
  const float t0 = sqrtf(1.f + tsq);            // tail time component

  float neg_inner = fmaf(ht0, t0, -dot);        // -lorentz_inner
  float ic   = fmaxf(neg_inner, 1.0f + 1e-6f);
  float dist = acoshf(ic);
  if (gid < n) out[gid] = bsum - dist * dist;
}

// ---------------------------------------------------------------------------
// Fallback (ws too small): fully inline fp32 scalar path (R1, proven).
// ---------------------------------------------------------------------------
__global__ __launch_bounds__(256) void lorentz_fallback_kernel(
    const int* __restrict__ heads, const int* __restrict__ rels,
    const int* __restrict__ tails, const float* __restrict__ emb,
    const float* __restrict__ boost_w, const float* __restrict__ rot_w,
    const float* __restrict__ trans_w, const float* __restrict__ bias,
    float* __restrict__ out, int n) {
  int i = blockIdx.x * blockDim.x + threadIdx.x;
  if (i >= n) return;
  int hd = heads[i], rl = rels[i], tl = tails[i];
  const float* hrow = emb + (size_t)hd * EMB_DIM;
  const float* trow = emb + (size_t)tl * EMB_DIM;
  const float* ro = rot_w   + (size_t)rl * D_;
  const float* tr = trans_w + (size_t)rl * D_;
  float c[HALF_], s[HALF_], kt[D_];
  #pragma unroll
  for (int j = 0; j < HALF_; ++j) { float th = ro[j]; c[j] = cosf(th); s[j] = sinf(th); }
  float s2 = 0.f;
  #pragma unroll
  for (int j = 0; j < D_; ++j) { float v = tr[j]; s2 = fmaf(v, v, s2); }
  float vn = sqrtf(fmaxf(0.01f * s2, 1e-6f));
  float cvn = coshf(vn);
  float k = sinhf(vn) / vn * 0.1f;
  #pragma unroll
  for (int j = 0; j < D_; ++j) kt[j] = k * tr[j];
  float rap = fminf(fmaxf(boost_w[(size_t)rl * D_], -2.f), 2.f);
  float c0 = coshf(rap), s0 = sinhf(rap);
  float x0 = hrow[0];
  float r[D_];
  #pragma unroll
  for (int j = 0; j < HALF_; ++j) {
    float a = hrow[1 + j], b = hrow[1 + HALF_ + j];
    r[j] = c[j] * a - s[j] * b;
    r[HALF_ + j] = s[j] * a + c[j] * b;
  }
  r[0] = fmaf(x0, s0, r[0] * c0);
  float t0 = trow[0], n2 = 0.f, dot = 0.f;
  #pragma unroll
  for (int j = 0; j < D_; ++j) {
    float rsv = fmaf(cvn, r[j], kt[j]);
    n2  = fmaf(rsv, rsv, n2);
    dot = fmaf(rsv, trow[1 + j], dot);
  }
  float ht0 = sqrtf(1.f + n2);
  float neg_inner = fmaf(ht0, t0, -dot);
  float ic = fmaxf(neg_inner, 1.0f + 1e-6f);
  float dist = acoshf(ic);
  out[i] = bias[hd] + bias[tl] - dist * dist;
}

extern "C" void kernel_launch(void* const* d_in, const int* in_sizes, int n_in,
                              void* d_out, int out_size, void* d_ws, size_t ws_size,
                              hipStream_t stream) {
  const int*   heads  = (const int*)d_in[0];
  const int*   rels   = (const int*)d_in[1];
  const int*   tails  = (const int*)d_in[2];
  const float* emb    = (const float*)d_in[3];
  const float* boostw = (const float*)d_in[4];
  const float* rotw   = (const float*)d_in[5];
  const float* transw = (const float*)d_in[6];
  const float* bias   = (const float*)d_in[7];
  float* out = (float*)d_out;
  int n = in_sizes[0];  // B = 1048576

  const size_t tab_bytes = (size_t)NR_ * TAB_STRIDE * sizeof(float);
  dim3 block(256);
  dim3 grid((n + 255) / 256);

  if (ws_size >= H16_BYTES + tab_bytes) {
    unsigned int* h16 = (unsigned int*)d_ws;
    float* tab = (float*)((char*)d_ws + H16_BYTES);
    prep_kernel<<<dim3(REPACK_BLOCKS + 4), block, 0, stream>>>(
        emb, boostw, rotw, transw, h16, tab);
    lorentz_h16_kernel<<<grid, block, 0, stream>>>(
        heads, rels, tails, h16, bias, tab, out, n);
  } else {
    lorentz_fallback_kernel<<<grid, block, 0, stream>>>(
        heads, rels, tails, emb, boostw, rotw, transw, bias, out, n);
  }
}

// Round 7
// 292.329 us; speedup vs baseline: 1.0195x; 1.0195x over previous
//
#include <hip/hip_runtime.h>
#include <hip/hip_fp16.h>
#include <math.h>

// Problem constants: NE=1e6, NR=1000, D=32, B=2^20, CURV=1
#define NR_ 1000
#define NE_ 1000000
#define D_ 32
#define HALF_ 16
#define EMB_DIM 33            // fp32 entity row: [x0, spatial(32)]
#define TAB_STRIDE 68         // precomputed relation row (272 B)
#define LROW 17               // LDS uints per staged row (odd -> 2-way banks = free)
#define WSLOT (64 * LROW)     // 1088 uints per 64-row buffer
#define H16_BYTES ((size_t)NE_ * 64)   // fp16 table: 16 uints/row, 64 B-aligned rows
#define REPACK_BLOCKS 62500   // 62500*256 = 16,000,000 = NE*16 repack threads

// ---------------------------------------------------------------------------
// Kernel 0 (fused prep): blocks [0, REPACK_BLOCKS) repack entity spatials
// fp32 -> fp16 into 64 B-aligned rows (one line-touch per row gather after;
// also leaves the 64 MB table L2/L3-warm). Blocks [REPACK_BLOCKS, +4) build
// the per-relation table:
//   [0:16) cos(rot)  [16:32) sin(rot)  [32:64) (sinh(vn)/vn)*0.1*trans
//   [64] cosh(rap0) [65] sinh(rap0) [66] cosh(vn) [67] pad
// ---------------------------------------------------------------------------
__global__ __launch_bounds__(256) void prep_kernel(
    const float* __restrict__ emb, const float* __restrict__ boost_w,
    const float* __restrict__ rot_w, const float* __restrict__ trans_w,
    unsigned int* __restrict__ h16, float* __restrict__ tab) {
  const int b = blockIdx.x;
  if (b < REPACK_BLOCKS) {
    int t = b * 256 + threadIdx.x;              // < 16,000,000
    int r = t >> 4, j = t & 15;
    const float* p = emb + (size_t)r * EMB_DIM + 1 + 2 * j;
    union { __half2 h; unsigned int u; } cvt;
    cvt.h = __half2(__float2half_rn(p[0]), __float2half_rn(p[1]));
    h16[t] = cvt.u;
    return;
  }
  int r = (b - REPACK_BLOCKS) * 256 + threadIdx.x;
  if (r >= NR_) return;
  const float* ro = rot_w   + (size_t)r * D_;
  const float* tr = trans_w + (size_t)r * D_;
  float* o = tab + (size_t)r * TAB_STRIDE;
  #pragma unroll
  for (int j = 0; j < HALF_; ++j) {
    float th = ro[j];
    o[j]         = cosf(th);
    o[HALF_ + j] = sinf(th);
  }
  float s2 = 0.f;
  #pragma unroll
  for (int j = 0; j < D_; ++j) { float v = tr[j]; s2 = fmaf(v, v, s2); }
  float vn  = sqrtf(fmaxf(0.01f * s2, 1e-6f));
  float k   = sinhf(vn) / vn * 0.1f;
  #pragma unroll
  for (int j = 0; j < D_; ++j) o[2 * HALF_ + j] = k * tr[j];
  float rap = fminf(fmaxf(boost_w[(size_t)r * D_], -2.f), 2.f);
  o[64] = coshf(rap);
  o[65] = sinhf(rap);
  o[66] = coshf(vn);
  o[67] = 0.f;
}

// ---------------------------------------------------------------------------
// Kernel 1: main scoring, MAX-MLP variant. Block=256 (4 waves); each wave
// owns 64 elements + TWO private LDS row-buffers (head + tail, 8704 B/wave,
// 34816 B/block -> 4 blocks/CU = 16 waves/CU, >= the measured 14). All 8
// gather instructions (4 head + 4 tail) issue back-to-back with no
// intervening dependency -> 2x outstanding line-fetches vs R6. Barrier-free
// (per-wave DS program order). fp16 rows unpacked on LDS read.
// Banks: reads (lane*17+u)%32 -> 2 lanes/bank (free, m136); writes
// (17e+4q+m)%32 uniform 2/bank (free; measured 2.5% conflict cycles in R6).
// x0/t0 recomputed as sqrt(1+sum(sp^2)) — the reference's own formula.
// ---------------------------------------------------------------------------
__global__ __launch_bounds__(256) void lorentz_mlp_kernel(
    const int* __restrict__ heads, const int* __restrict__ rels,
    const int* __restrict__ tails, const unsigned int* __restrict__ h16,
    const float* __restrict__ bias, const float* __restrict__ tab,
    float* __restrict__ out, int n) {
  __shared__ unsigned int buf[4][2 * WSLOT];   // 34816 B/block

  const int lane = threadIdx.x & 63;
  const int w    = threadIdx.x >> 6;
  const int gid  = blockIdx.x * 256 + threadIdx.x;
  const int i    = (gid < n) ? gid : (n - 1);   // clamp: lanes stay active

  const int hd = heads[i];
  const int rl = rels[i];
  const int tl = tails[i];
  const float bsum = bias[hd] + bias[tl];
  const float4* __restrict__ T =
      reinterpret_cast<const float4*>(tab + (size_t)rl * TAB_STRIDE);

  unsigned int* __restrict__ hb = buf[w];
  unsigned int* __restrict__ tb = buf[w] + WSLOT;
  const int esub = lane >> 2;   // 0..15
  const int q    = lane & 3;    // 16 B chunk within row

  // ---- Issue ALL gathers up front: 4 head + 4 tail loads, no dependency
  // between them (the compiler interleaves global_load + ds_write; vmcnt
  // allows 8 outstanding vector loads per wave = 128 lines in flight) ----
  #pragma unroll
  for (int k = 0; k < 4; ++k) {
    const int e   = k * 16 + esub;
    const int row = __shfl(hd, e, 64);
    const uint4 v = *reinterpret_cast<const uint4*>(
        h16 + (size_t)row * 16 + q * 4);        // 16 B-aligned, 1 line/row
    unsigned int* dst = hb + e * LROW + q * 4;
    dst[0] = v.x; dst[1] = v.y; dst[2] = v.z; dst[3] = v.w;
  }
  #pragma unroll
  for (int k = 0; k < 4; ++k) {
    const int e   = k * 16 + esub;
    const int row = __shfl(tl, e, 64);
    const uint4 v = *reinterpret_cast<const uint4*>(
        h16 + (size_t)row * 16 + q * 4);
    unsigned int* dst = tb + e * LROW + q * 4;
    dst[0] = v.x; dst[1] = v.y; dst[2] = v.z; dst[3] = v.w;
  }

  // ---- Head compute: unpack own row, rotation + boost + translation ----
  const unsigned int* __restrict__ myh = hb + lane * LROW;
  union U2 { unsigned int u; __half2 h; };
  float a[HALF_], b[HALF_];
  #pragma unroll
  for (int uu = 0; uu < 8; ++uu) {
    U2 ua; ua.u = myh[uu];        // elements 2uu, 2uu+1     (a-half)
    U2 ub; ub.u = myh[8 + uu];    // elements 16+2uu, 17+2uu (b-half)
    float2 fa = __half22float2(ua.h);
    float2 fb = __half22float2(ub.h);
    a[2 * uu] = fa.x; a[2 * uu + 1] = fa.y;
    b[2 * uu] = fb.x; b[2 * uu + 1] = fb.y;
  }
  float r[D_];
  float hsq = 0.f;
  #pragma unroll
  for (int qq = 0; qq < 4; ++qq) {
    float4 cv = T[qq];
    float4 sv = T[4 + qq];
    float cj[4] = {cv.x, cv.y, cv.z, cv.w};
    float sj[4] = {sv.x, sv.y, sv.z, sv.w};
    #pragma unroll
    for (int m = 0; m < 4; ++m) {
      int j = 4 * qq + m;
      hsq = fmaf(a[j], a[j], fmaf(b[j], b[j], hsq));
      r[j]         = cj[m] * a[j] - sj[m] * b[j];
      r[HALF_ + j] = sj[m] * a[j] + cj[m] * b[j];
    }
  }
  const float x0 = sqrtf(1.f + hsq);            // head time component
  float4 hv4 = T[16];                           // {cosh(rap), sinh(rap), cosh(vn), -}
  r[0] = fmaf(x0, hv4.y, r[0] * hv4.x);
  const float cvn = hv4.z;

  float rs[D_];
  float n2 = 0.f;
  #pragma unroll
  for (int qq = 0; qq < 8; ++qq) {
    float4 kv = T[8 + qq];
    float kj[4] = {kv.x, kv.y, kv.z, kv.w};
    #pragma unroll
    for (int m = 0; m < 4; ++m) {
      int j = 4 * qq + m;
      rs[j] = fmaf(cvn, r[j], kj[m]);
      n2 = fmaf(rs[j], rs[j], n2);
    }
  }
  const float ht0 = sqrtf(1.f + n2);

  // ---- Tail dot from the second buffer (already staged; lgkm ordering) ----
  const unsigned int* __restrict__ myt = tb + lane * LROW;
  float dot = 0.f, tsq = 0.f;
  #pragma unroll
  for (int uu = 0; uu < 16; ++uu) {
    U2 ut; ut.u = myt[uu];
    float2 ft = __half22float2(ut.h);
    dot = fmaf(rs[2 * uu], ft.x, fmaf(rs[2 * uu + 1], ft.y, dot));
    tsq = fmaf(ft.x, ft.x, fmaf(ft.y, ft.y, tsq));
  }
  const float t0 = sqrtf(1.f + tsq);            // tail time component

  float neg_inner = fmaf(ht0, t0, -dot);        // -lorentz_inner
  float ic   = fmaxf(neg_inner, 1.0f + 1e-6f);
  float dist = acoshf(ic);
  if (gid < n) out[gid] = bsum - dist * dist;
}

// ---------------------------------------------------------------------------
// Fallback (ws too small): fully inline fp32 scalar path (R1, proven).
// ---------------------------------------------------------------------------
__global__ __launch_bounds__(256) void lorentz_fallback_kernel(
    const int* __restrict__ heads, const int* __restrict__ rels,
    const int* __restrict__ tails, const float* __restrict__ emb,
    const float* __restrict__ boost_w, const float* __restrict__ rot_w,
    const float* __restrict__ trans_w, const float* __restrict__ bias,
    float* __restrict__ out, int n) {
  int i = blockIdx.x * blockDim.x + threadIdx.x;
  if (i >= n) return;
  int hd = heads[i], rl = rels[i], tl = tails[i];
  const float* hrow = emb + (size_t)hd * EMB_DIM;
  const float* trow = emb + (size_t)tl * EMB_DIM;
  const float* ro = rot_w   + (size_t)rl * D_;
  const float* tr = trans_w + (size_t)rl * D_;
  float c[HALF_], s[HALF_], kt[D_];
  #pragma unroll
  for (int j = 0; j < HALF_; ++j) { float th = ro[j]; c[j] = cosf(th); s[j] = sinf(th); }
  float s2 = 0.f;
  #pragma unroll
  for (int j = 0; j < D_; ++j) { float v = tr[j]; s2 = fmaf(v, v, s2); }
  float vn = sqrtf(fmaxf(0.01f * s2, 1e-6f));
  float cvn = coshf(vn);
  float k = sinhf(vn) / vn * 0.1f;
  #pragma unroll
  for (int j = 0; j < D_; ++j) kt[j] = k * tr[j];
  float rap = fminf(fmaxf(boost_w[(size_t)rl * D_], -2.f), 2.f);
  float c0 = coshf(rap), s0 = sinhf(rap);
  float x0 = hrow[0];
  float r[D_];
  #pragma unroll
  for (int j = 0; j < HALF_; ++j) {
    float a = hrow[1 + j], b = hrow[1 + HALF_ + j];
    r[j] = c[j] * a - s[j] * b;
    r[HALF_ + j] = s[j] * a + c[j] * b;
  }
  r[0] = fmaf(x0, s0, r[0] * c0);
  float t0 = trow[0], n2 = 0.f, dot = 0.f;
  #pragma unroll
  for (int j = 0; j < D_; ++j) {
    float rsv = fmaf(cvn, r[j], kt[j]);
    n2  = fmaf(rsv, rsv, n2);
    dot = fmaf(rsv, trow[1 + j], dot);
  }
  float ht0 = sqrtf(1.f + n2);
  float neg_inner = fmaf(ht0, t0, -dot);
  float ic = fmaxf(neg_inner, 1.0f + 1e-6f);
  float dist = acoshf(ic);
  out[i] = bias[hd] + bias[tl] - dist * dist;
}

extern "C" void kernel_launch(void* const* d_in, const int* in_sizes, int n_in,
                              void* d_out, int out_size, void* d_ws, size_t ws_size,
                              hipStream_t stream) {
  const int*   heads  = (const int*)d_in[0];
  const int*   rels   = (const int*)d_in[1];
  const int*   tails  = (const int*)d_in[2];
  const float* emb    = (const float*)d_in[3];
  const float* boostw = (const float*)d_in[4];
  const float* rotw   = (const float*)d_in[5];
  const float* transw = (const float*)d_in[6];
  const float* bias   = (const float*)d_in[7];
  float* out = (float*)d_out;
  int n = in_sizes[0];  // B = 1048576

  const size_t tab_bytes = (size_t)NR_ * TAB_STRIDE * sizeof(float);
  dim3 block(256);
  dim3 grid((n + 255) / 256);

  if (ws_size >= H16_BYTES + tab_bytes) {
    unsigned int* h16 = (unsigned int*)d_ws;
    float* tab = (float*)((char*)d_ws + H16_BYTES);
    prep_kernel<<<dim3(REPACK_BLOCKS + 4), block, 0, stream>>>(
        emb, boostw, rotw, transw, h16, tab);
    lorentz_mlp_kernel<<<grid, block, 0, stream>>>(
        heads, rels, tails, h16, bias, tab, out, n);
  } else {
    lorentz_fallback_kernel<<<grid, block, 0, stream>>>(
        heads, rels, tails, emb, boostw, rotw, transw, bias, out, n);
  }
}